// Round 16
// baseline (165.021 us; speedup 1.0000x reference)
//
#include <hip/hip_runtime.h>
#include <math.h>

#define B_DIM 16384
#define D_DIM 64
#define H_DIM 1024
#define CLAMP_V 10.0f

typedef __fp16 h2 __attribute__((ext_vector_type(2)));

// Hidden-dim permutation: sort h by m0(h) = h % 63 (stable).
// pos(c) = 16*c + min(c,16). INVERSE (verified since round 4): given hp,
//   hp<272: c=hp/17, q=hp%17; else c=(hp-272)/16+16, q=(hp-272)%16; h=63q+c.
__device__ __forceinline__ void inv_perm(int hp, int &c, int &h) {
    int q;
    if (hp < 272) { c = hp / 17; q = hp % 17; }
    else          { c = ((hp - 272) >> 4) + 16; q = (hp - 272) & 15; }
    h = (D_DIM - 1) * q + c;
}

// ---------------------------------------------------------------------------
// Prep v3: ZERO irregular global accesses. Permutation gather happens in LDS.
// Evidence: rounds with any irregular-scatter side in prep (fwd writes R2-R14,
// inv reads R15) showed a 30-54 us total-minus-main gap; R1/R3 (no scatter)
// showed ~0. Blocks 0-127: W2 rows; 128-131: W1 16-wide i-bands (LDS
// transpose); 132: b1.
// ---------------------------------------------------------------------------
__global__ void maf_prep_kernel(const float* __restrict__ W1,
                                const float* __restrict__ W2,
                                const float* __restrict__ b1,
                                __fp16* __restrict__ W1h,
                                __fp16* __restrict__ W2h,
                                __fp16* __restrict__ b1p) {
    __shared__ __fp16 lds[16 * H_DIM];          // 32 KB, reused by all roles
    const int blk = blockIdx.x;
    const int t = threadIdx.x;

    if (blk < 2 * D_DIM) {                      // ---- W2 row j ----
        const int j = blk, cj = j >> 1;
#pragma unroll
        for (int p = 0; p < 4; p++) {           // coalesced f32 loads
            int h = t + 256 * p;
            float v = W2[j * H_DIM + h];
            int m0 = h % (D_DIM - 1);
            lds[h] = (__fp16)((m0 < cj) ? v : 0.0f);
        }
        __syncthreads();
#pragma unroll
        for (int p = 0; p < 4; p++) {           // LDS gather + coalesced store
            int hp = t + 256 * p;
            int c, h;
            inv_perm(hp, c, h);
            W2h[j * H_DIM + hp] = lds[h];
        }
    } else if (blk < 2 * D_DIM + 4) {           // ---- W1 i-band ----
        const int i0 = (blk - 2 * D_DIM) * 16;
        const int il = t & 15;                  // i-local
        const int hb = t >> 4;                  // h-base (16 h per pass)
        const int i = i0 + il;
#pragma unroll
        for (int p = 0; p < 64; p++) {          // 64B-segment coalesced loads
            int h = hb + p * 16;
            float v = W1[h * D_DIM + i];
            int m0 = h % (D_DIM - 1);
            lds[h * 16 + il] = (__fp16)((i <= m0) ? v : 0.0f);
        }
        __syncthreads();
        int hs[4];
#pragma unroll
        for (int p = 0; p < 4; p++) {           // h(hp) once per thread
            int c, h;
            inv_perm(t + 256 * p, c, h);
            hs[p] = h;
        }
        for (int ii = 0; ii < 16; ii++) {       // coalesced 2B stores
#pragma unroll
            for (int p = 0; p < 4; p++)
                W1h[(i0 + ii) * H_DIM + t + 256 * p] = lds[hs[p] * 16 + ii];
        }
    } else {                                    // ---- b1 ----
#pragma unroll
        for (int p = 0; p < 4; p++) {
            int h = t + 256 * p;
            lds[h] = (__fp16)b1[h];
        }
        __syncthreads();
#pragma unroll
        for (int p = 0; p < 4; p++) {
            int hp = t + 256 * p;
            int c, h;
            inv_perm(hp, c, h);
            b1p[hp] = lds[h];
        }
    }
}

// Cubic packed-f16 tanh (rounds 10-15 verified, absmax 0.0156): |s| <= ~0.02.
__device__ __forceinline__ h2 tanh_h2(h2 x) {
    h2 x2 = x * x;
    h2 p = __builtin_elementwise_fma(
        x2, h2{(__fp16)-0.33333333f, (__fp16)-0.33333333f},
        h2{(__fp16)1.0f, (__fp16)1.0f});
    return x * p;
}

__device__ __forceinline__ float clampv(float v) {
    return fminf(fmaxf(v, -CLAMP_V), CLAMP_V);
}
__device__ __forceinline__ h2 pkfma(h2 a, h2 b, h2 c) {
    return __builtin_elementwise_fma(a, b, c);
}
__device__ __forceinline__ float readlane_f(float v, int l) {
    return __int_as_float(__builtin_amdgcn_readlane(__float_as_int(v), l));
}

// Rotate-allreduce within each 16-lane DPP row (= one elem group).
template<int CTRL>
__device__ __forceinline__ float dpp_add_(float v) {
    int m = __builtin_amdgcn_update_dpp(0, __float_as_int(v), CTRL, 0xf, 0xf, true);
    return v + __int_as_float(m);
}
__device__ __forceinline__ float rowsum16(float v) {
    v = dpp_add_<0x121>(v);   // row_ror:1
    v = dpp_add_<0x122>(v);   // row_ror:2
    v = dpp_add_<0x124>(v);   // row_ror:4
    v = dpp_add_<0x128>(v);   // row_ror:8
    return v;
}

// ---------------------------------------------------------------------------
// One step. PH = i&3 (compile-time). Consumes W2/W1/z buffers C (prefetched
// LAST step — full-step cover); prefetches (i+1)'s into N. Multi-accumulator
// dots (alpha 4-way, mu 2-way) shorten the serial pkfma chains.
// ---------------------------------------------------------------------------
template<int MU, int AL, int UL, int PH>
__device__ __forceinline__ void do_step(
    int i, int r,
    float4 (&wmC)[2 * MU], float4 (&waC)[2 * AL], float4 (&w1C)[2 * (4 - UL)],
    float4 (&wmN)[2 * MU], float4 (&waN)[2 * AL], float4 (&w1N)[2 * (4 - UL)],
    float zC0, float zC1, float &zN0, float &zN1,
    h2 (&s)[2][4][8], float4 (&xr)[2], float (&ld)[2],
    const float* __restrict__ zrow0, const float* __restrict__ zrow1,
    float b2m_v, float b2a_v,
    const __fp16* __restrict__ W1h, const __fp16* __restrict__ W2h)
{
    const int ip = (i + 1) & 63;
    // prefetch next step's W2 rows, W1 column, and z (consumed next step)
    {
        const float4* wmp = reinterpret_cast<const float4*>(W2h + ip * H_DIM) + r * 2;
        const float4* wap = reinterpret_cast<const float4*>(W2h + (D_DIM + ip) * H_DIM) + r * 2;
        const float4* w1p = reinterpret_cast<const float4*>(W1h + ip * H_DIM) + r * 2;
#pragma unroll
        for (int k = 0; k < MU; k++) {       // chunk stride = 512 B = 32 float4
            wmN[2 * k]     = wmp[k * 32];
            wmN[2 * k + 1] = wmp[k * 32 + 1];
        }
#pragma unroll
        for (int k = 0; k < AL; k++) {
            waN[2 * k]     = wap[k * 32];
            waN[2 * k + 1] = wap[k * 32 + 1];
        }
#pragma unroll
        for (int k = 0; k < 4 - UL; k++) {
            w1N[2 * k]     = w1p[(UL + k) * 32];
            w1N[2 * k + 1] = w1p[(UL + k) * 32 + 1];
        }
        zN0 = zrow0[ip];
        zN1 = zrow1[ip];
    }

    const float b2mu = readlane_f(b2m_v, i);
    const float b2al = readlane_f(b2a_v, i);

    float dm[2], da[2];
#pragma unroll
    for (int e = 0; e < 2; e++) {
        const h2 z0 = h2{(__fp16)0.0f, (__fp16)0.0f};
        h2 aM0 = z0, aM1 = z0;
        h2 aA0 = z0, aA1 = z0, aA2 = z0, aA3 = z0;
#pragma unroll
        for (int k = 0; k < AL; k++) {
            const float* wmf = reinterpret_cast<const float*>(&wmC[2 * k]);
            const float* waf = reinterpret_cast<const float*>(&waC[2 * k]);
#pragma unroll
            for (int j = 0; j < 8; j++) {
                h2 p = (k < UL) ? s[e][k][j] : tanh_h2(s[e][k][j]);
                if (k < MU) {
                    if (j & 1) aM1 = pkfma(p, __builtin_bit_cast(h2, wmf[j]), aM1);
                    else       aM0 = pkfma(p, __builtin_bit_cast(h2, wmf[j]), aM0);
                }
                switch (j & 3) {
                    case 0: aA0 = pkfma(p, __builtin_bit_cast(h2, waf[j]), aA0); break;
                    case 1: aA1 = pkfma(p, __builtin_bit_cast(h2, waf[j]), aA1); break;
                    case 2: aA2 = pkfma(p, __builtin_bit_cast(h2, waf[j]), aA2); break;
                    case 3: aA3 = pkfma(p, __builtin_bit_cast(h2, waf[j]), aA3); break;
                }
            }
        }
        h2 aM = aM0 + aM1;
        h2 aA = (aA0 + aA1) + (aA2 + aA3);
        dm[e] = rowsum16((float)aM.x + (float)aM.y);
        da[e] = rowsum16((float)aA.x + (float)aA.y);
    }

    const bool mine = (r == (i >> 2));   // lane r owns outputs i in [4r,4r+4)
#pragma unroll
    for (int e = 0; e < 2; e++) {
        float mu = clampv(dm[e] + b2mu);
        float al = clampv(da[e] + b2al);
        float zi = (e == 0) ? zC0 : zC1;
        float xi = fmaf(zi, __expf(al), mu);
        ld[e] += al;
        if (PH == 0) xr[e].x = mine ? xi : xr[e].x;
        if (PH == 1) xr[e].y = mine ? xi : xr[e].y;
        if (PH == 2) xr[e].z = mine ? xi : xr[e].z;
        if (PH == 3) xr[e].w = mine ? xi : xr[e].w;
        __fp16 xh = (__fp16)xi;
        h2 xi2 = h2{xh, xh};
#pragma unroll
        for (int k = UL; k < 4; k++) {   // packed-f16 rank-1 update
            const float* w1f = reinterpret_cast<const float*>(&w1C[2 * (k - UL)]);
#pragma unroll
            for (int j = 0; j < 8; j++)
                s[e][k][j] = pkfma(xi2, __builtin_bit_cast(h2, w1f[j]), s[e][k][j]);
        }
    }
}

// ---------------------------------------------------------------------------
// One 16-step phase: 4-step unrolled body keeps A/B buffer parity static AND
// i&3 compile-time. Buffers A preloaded at phase entry.
// ---------------------------------------------------------------------------
template<int MU, int AL, int UL>
__device__ __forceinline__ void run_phase(
    int i0, int r, h2 (&s)[2][4][8], float4 (&xr)[2], float (&ld)[2],
    const float* __restrict__ zrow0, const float* __restrict__ zrow1,
    float b2m_v, float b2a_v,
    const __fp16* __restrict__ W1h, const __fp16* __restrict__ W2h)
{
    float4 wmA[2 * MU], waA[2 * AL], w1A[2 * (4 - UL)];
    float4 wmB[2 * MU], waB[2 * AL], w1B[2 * (4 - UL)];
    float zA0, zA1, zB0, zB1;
    {   // preload buffers A + z for first step of phase
        const float4* wmp = reinterpret_cast<const float4*>(W2h + i0 * H_DIM) + r * 2;
        const float4* wap = reinterpret_cast<const float4*>(W2h + (D_DIM + i0) * H_DIM) + r * 2;
        const float4* w1p = reinterpret_cast<const float4*>(W1h + i0 * H_DIM) + r * 2;
#pragma unroll
        for (int k = 0; k < MU; k++) {
            wmA[2 * k]     = wmp[k * 32];
            wmA[2 * k + 1] = wmp[k * 32 + 1];
        }
#pragma unroll
        for (int k = 0; k < AL; k++) {
            waA[2 * k]     = wap[k * 32];
            waA[2 * k + 1] = wap[k * 32 + 1];
        }
#pragma unroll
        for (int k = 0; k < 4 - UL; k++) {
            w1A[2 * k]     = w1p[(UL + k) * 32];
            w1A[2 * k + 1] = w1p[(UL + k) * 32 + 1];
        }
        zA0 = zrow0[i0];
        zA1 = zrow1[i0];
    }
#pragma unroll 1
    for (int p = 0; p < 4; p++) {
        const int base = i0 + 4 * p;
        do_step<MU, AL, UL, 0>(base + 0, r, wmA, waA, w1A, wmB, waB, w1B,
                               zA0, zA1, zB0, zB1, s, xr, ld,
                               zrow0, zrow1, b2m_v, b2a_v, W1h, W2h);
        do_step<MU, AL, UL, 1>(base + 1, r, wmB, waB, w1B, wmA, waA, w1A,
                               zB0, zB1, zA0, zA1, s, xr, ld,
                               zrow0, zrow1, b2m_v, b2a_v, W1h, W2h);
        do_step<MU, AL, UL, 2>(base + 2, r, wmA, waA, w1A, wmB, waB, w1B,
                               zA0, zA1, zB0, zB1, s, xr, ld,
                               zrow0, zrow1, b2m_v, b2a_v, W1h, W2h);
        do_step<MU, AL, UL, 3>(base + 3, r, wmB, waB, w1B, wmA, waA, w1A,
                               zB0, zB1, zA0, zA1, s, xr, ld,
                               zrow0, zrow1, b2m_v, b2a_v, W1h, W2h);
    }
}

// ---------------------------------------------------------------------------
// Main: 16 lanes per elem-slot, 4 slots x E=2 stacked = 8 elems/wave;
// 4 waves/block; 512 blocks = 2048 waves = 2/SIMD (all resident).
// __launch_bounds__(256,1): cap 256 — demand ~100, no spill.
// ---------------------------------------------------------------------------
__global__ __launch_bounds__(256, 1) void maf_main_kernel(
    const float* __restrict__ z, const float* __restrict__ b2,
    const __fp16* __restrict__ W1h, const __fp16* __restrict__ W2h,
    const __fp16* __restrict__ b1p, float* __restrict__ out)
{
    const int wave = threadIdx.x >> 6;
    const int lane = threadIdx.x & 63;
    const int g = lane >> 4;
    const int r = lane & 15;
    const int bw = (blockIdx.x * 4 + wave) * 8;
    const int b0 = bw + g;          // e=0 elem
    const int b1i = bw + 4 + g;     // e=1 elem

    h2 s[2][4][8];
    const h2* b1p2 = reinterpret_cast<const h2*>(b1p);
#pragma unroll
    for (int c = 0; c < 4; c++) {
        int base = c * 128 + r * 8;
#pragma unroll
        for (int j = 0; j < 8; j++) {
            h2 v = b1p2[base + j];
            s[0][c][j] = v;
            s[1][c][j] = v;
        }
    }

    const float* zrow0 = z + b0 * D_DIM;
    const float* zrow1 = z + b1i * D_DIM;
    const float b2m_v = b2[lane];            // b2[i] via readlane(i)
    const float b2a_v = b2[D_DIM + lane];    // b2[64+i] via readlane(i)
    float4 xr[2] = {float4{0,0,0,0}, float4{0,0,0,0}};
    float ld[2] = {0.0f, 0.0f};

    run_phase<1, 3, 0>(0, r, s, xr, ld, zrow0, zrow1, b2m_v, b2a_v, W1h, W2h);
#pragma unroll
    for (int e = 0; e < 2; e++)
#pragma unroll
        for (int j = 0; j < 8; j++) s[e][0][j] = tanh_h2(s[e][0][j]);
    run_phase<1, 3, 1>(16, r, s, xr, ld, zrow0, zrow1, b2m_v, b2a_v, W1h, W2h);
#pragma unroll
    for (int e = 0; e < 2; e++)
#pragma unroll
        for (int j = 0; j < 8; j++) s[e][1][j] = tanh_h2(s[e][1][j]);
    run_phase<2, 4, 2>(32, r, s, xr, ld, zrow0, zrow1, b2m_v, b2a_v, W1h, W2h);
#pragma unroll
    for (int e = 0; e < 2; e++)
#pragma unroll
        for (int j = 0; j < 8; j++) s[e][2][j] = tanh_h2(s[e][2][j]);
    run_phase<2, 4, 3>(48, r, s, xr, ld, zrow0, zrow1, b2m_v, b2a_v, W1h, W2h);

#pragma unroll
    for (int e = 0; e < 2; e++) {
        float4 v = xr[e];
        v.x = isfinite(v.x) ? v.x : 0.0f;
        v.y = isfinite(v.y) ? v.y : 0.0f;
        v.z = isfinite(v.z) ? v.z : 0.0f;
        v.w = isfinite(v.w) ? v.w : 0.0f;
        int b = (e == 0) ? b0 : b1i;
        *reinterpret_cast<float4*>(out + b * D_DIM + r * 4) = v;  // coalesced
        if (r == 0) {
            float l = isfinite(ld[e]) ? ld[e] : 0.0f;
            out[B_DIM * D_DIM + b] = l;
        }
    }
}

extern "C" void kernel_launch(void* const* d_in, const int* in_sizes, int n_in,
                              void* d_out, int out_size, void* d_ws, size_t ws_size,
                              hipStream_t stream) {
    const float* z  = (const float*)d_in[0];   // (B, D)
    const float* W1 = (const float*)d_in[1];   // (H, D)
    const float* b1 = (const float*)d_in[2];   // (H,)
    const float* W2 = (const float*)d_in[3];   // (2D, H)
    const float* b2 = (const float*)d_in[4];   // (2D,)
    float* out = (float*)d_out;                // x (B*D) then log_det (B)

    __fp16* W1h = (__fp16*)d_ws;               // D*H f16   (128 KB)
    __fp16* W2h = W1h + D_DIM * H_DIM;         // 2D*H f16  (256 KB)
    __fp16* b1p = W2h + 2 * D_DIM * H_DIM;     // H f16     (2 KB)

    // 128 W2-row blocks + 4 W1-band blocks + 1 b1 block = 133
    maf_prep_kernel<<<133, 256, 0, stream>>>(W1, W2, b1, W1h, W2h, b1p);

    // 16384 elems / 8 per wave / 4 waves per block = 512 blocks
    maf_main_kernel<<<B_DIM / 32, 256, 0, stream>>>(z, b2, W1h, W2h, b1p, out);
}